// Round 6
// baseline (399.209 us; speedup 1.0000x reference)
//
#include <hip/hip_runtime.h>
#include <cstdint>

typedef __bf16 bf16;
typedef __bf16 bf16x8 __attribute__((ext_vector_type(8)));
typedef __bf16 bf16x4 __attribute__((ext_vector_type(4)));
typedef float  f32x4  __attribute__((ext_vector_type(4)));

#define SEQ  2048
#define HID  4096
#define DH   128
#define NQH  32
#define NKVH 8
#define NTOT 6144            /* 4096 q + 1024 k + 1024 v */
#define RSCALE 0.08838834764831845f   /* 1/sqrt(128) */
#define SOFTCAP 30.0f
#define L2E 1.4426950408889634f

// async global->LDS, 16B per lane; LDS dest = wave-uniform base + lane*16
__device__ __forceinline__ void gl2lds16(const void* g, void* l) {
  __builtin_amdgcn_global_load_lds(
      (const __attribute__((address_space(1))) unsigned int*)g,
      (__attribute__((address_space(3))) unsigned int*)l, 16, 0, 0);
}

// ---------------------------------------------------------------------------
// fp32 -> bf16 conversion (vectorized)
// ---------------------------------------------------------------------------
__global__ void cvt_kernel(const float* __restrict__ in, bf16* __restrict__ out, int n4) {
  const int stride = gridDim.x * blockDim.x;
  for (int i = blockIdx.x * blockDim.x + threadIdx.x; i < n4; i += stride) {
    const float4 v = ((const float4*)in)[i];
    bf16x4 o = { (bf16)v.x, (bf16)v.y, (bf16)v.z, (bf16)v.w };
    *(bf16x4*)(out + (size_t)i * 4) = o;
  }
}

// ---------------------------------------------------------------------------
// pre-attention RMSNorm: (S,H) fp32 -> bf16; also copies residual into d_out
// (O-proj later accumulates via fp32 atomicAdd on top of it).
// ---------------------------------------------------------------------------
__global__ void rmsnorm_kernel(const float* __restrict__ x, const float* __restrict__ w,
                               bf16* __restrict__ out, float* __restrict__ res_out) {
  const int s = blockIdx.x;
  const float* xr = x + (size_t)s * HID;
  float4 v[4];
  float ss = 0.f;
#pragma unroll
  for (int j = 0; j < 4; ++j) {
    v[j] = ((const float4*)xr)[threadIdx.x + j * 256];
    ss += v[j].x * v[j].x + v[j].y * v[j].y + v[j].z * v[j].z + v[j].w * v[j].w;
  }
#pragma unroll
  for (int m = 1; m < 64; m <<= 1) ss += __shfl_xor(ss, m);
  __shared__ float red[4];
  if ((threadIdx.x & 63) == 0) red[threadIdx.x >> 6] = ss;
  __syncthreads();
  const float rn = rsqrtf((red[0] + red[1] + red[2] + red[3]) * (1.f / HID) + 1e-5f);
  bf16* orow = out + (size_t)s * HID;
  float4* rrow = (float4*)(res_out + (size_t)s * HID);
#pragma unroll
  for (int j = 0; j < 4; ++j) {
    const int idx = (threadIdx.x + j * 256) * 4;
    const float4 wv = ((const float4*)w)[threadIdx.x + j * 256];
    bf16x4 o = { (bf16)(v[j].x * rn * wv.x), (bf16)(v[j].y * rn * wv.y),
                 (bf16)(v[j].z * rn * wv.z), (bf16)(v[j].w * rn * wv.w) };
    *(bf16x4*)(orow + idx) = o;
    rrow[threadIdx.x + j * 256] = v[j];   // residual copy
  }
}

// ---------------------------------------------------------------------------
// Ring-buffered 256x256 GEMM  C[M,N] = A[M,K] * B[N,K]^T
// 512 threads = 8 waves (2m x 4n), wave tile 128x64.
// K chunked at 32; LDS ring of 5 slots x 32KB (A 16KB + B 16KB) = 160 KB.
// Prefetch distance 4 chunks (16 loads in flight), counted vmcnt(12) steady
// state -> each chunk's loads get ~3 iterations (~1200 cyc) of slack and the
// VMEM queue never drains. One barrier + one lgkmcnt(0) per 32 MFMA.
// Ring safety: at iter c we stage slot (c+4)%5 (chunk c-1's old slot); every
// wave finished reading chunk c-1 (own lgkmcnt(0)) before the end-of-(c-1)
// barrier, which precedes any iter-c stage issue. Chunk c's loads were
// vmcnt-retired by end of iter c-1 across all waves, then barrier-published.
// FINAL: fp32 atomicAdd into Cf (split-K partials; Cf pre-filled w/ residual).
// ---------------------------------------------------------------------------
template<bool FINAL>
__global__ __launch_bounds__(512, 1)
void gemmring(const bf16* __restrict__ A, const bf16* __restrict__ B,
              bf16* __restrict__ Cb, float* __restrict__ Cf,
              int M, int N, int Ktot, int Klen)
{
  extern __shared__ char smem[];   // 5 x 32768
  const int tid  = threadIdx.x;
  const int lane = tid & 63;
  const int wave = tid >> 6;
  const int wm = wave >> 2, wn = wave & 3;

  // XCD-aware bijective swizzle within a z-slice (nwg % 8 == 0)
  const int gx = gridDim.x;
  const int nwg = gx * gridDim.y;
  int lin = blockIdx.x + gx * blockIdx.y;
  lin = (lin & 7) * (nwg >> 3) + (lin >> 3);
  const int m0 = (lin / gx) * 256;
  const int n0 = (lin % gx) * 256;
  const int k0 = blockIdx.z * Klen;

  // stage chunk c into ring slot sl. Per thread: 2 A loads + 2 B loads.
  // LDS row layout: 32 bf16 (64B) rows; col-group g' = g ^ (r&3) swizzle,
  // applied by pre-swizzling the global source column.
  const int rsub = lane >> 2;                              // row within 16-row piece
  const int g8   = (((lane & 3) ^ (rsub & 3))) * 8;        // source col offset (elems)
  auto stage = [&](int c, int sl) {
    const int kt = k0 + c * 32;
    char* base = smem + sl * 32768;
#pragma unroll
    for (int l = 0; l < 2; ++l) {
      const int p = wave * 2 + l;
      gl2lds16(A + (size_t)(m0 + p * 16 + rsub) * Ktot + kt + g8, base + p * 1024);
    }
#pragma unroll
    for (int l = 0; l < 2; ++l) {
      const int p = wave * 2 + l;
      gl2lds16(B + (size_t)(n0 + p * 16 + rsub) * Ktot + kt + g8, base + 16384 + p * 1024);
    }
  };

  f32x4 acc[8][4] = {};
  const int n_ch = Klen / 32;

  // read-side addressing
  const int rl = lane & 15;
  const int sw = ((lane >> 4) ^ (lane & 3)) * 8;   // swizzled col offset (elems)

  // prologue: 4 chunks in flight
  stage(0, 0); stage(1, 1); stage(2, 2); stage(3, 3);
  asm volatile("s_waitcnt vmcnt(12)" ::: "memory");   // chunk 0 landed
  asm volatile("s_barrier" ::: "memory");

  int rs = 0, ss = 4;
  for (int c = 0; c < n_ch; ++c) {
    if (c + 4 < n_ch) stage(c + 4, ss);
    const bf16* Ab = (const bf16*)(smem + rs * 32768);
    const bf16* Bb = (const bf16*)(smem + rs * 32768 + 16384);
    bf16x8 afr[8], bfr[4];
#pragma unroll
    for (int mi = 0; mi < 8; ++mi)
      afr[mi] = *(const bf16x8*)(Ab + (wm * 128 + mi * 16 + rl) * 32 + sw);
#pragma unroll
    for (int ni = 0; ni < 4; ++ni)
      bfr[ni] = *(const bf16x8*)(Bb + (wn * 64 + ni * 16 + rl) * 32 + sw);
    asm volatile("s_waitcnt lgkmcnt(0)" ::: "memory");
    __builtin_amdgcn_sched_barrier(0);
    __builtin_amdgcn_s_setprio(1);
#pragma unroll
    for (int mi = 0; mi < 8; ++mi)
#pragma unroll
      for (int ni = 0; ni < 4; ++ni)
        acc[mi][ni] = __builtin_amdgcn_mfma_f32_16x16x32_bf16(afr[mi], bfr[ni], acc[mi][ni], 0, 0, 0);
    __builtin_amdgcn_s_setprio(0);
    // counted wait: chunk c+1 must be resident before next iteration reads it
    if (c + 5 <= n_ch)      { asm volatile("s_waitcnt vmcnt(12)" ::: "memory"); }
    else if (c + 4 == n_ch) { asm volatile("s_waitcnt vmcnt(8)"  ::: "memory"); }
    else if (c + 3 == n_ch) { asm volatile("s_waitcnt vmcnt(4)"  ::: "memory"); }
    else if (c + 2 == n_ch) { asm volatile("s_waitcnt vmcnt(0)"  ::: "memory"); }
    asm volatile("s_barrier" ::: "memory");
    rs = (rs == 4) ? 0 : rs + 1;
    ss = (ss == 4) ? 0 : ss + 1;
  }

  // epilogue
#pragma unroll
  for (int mi = 0; mi < 8; ++mi) {
#pragma unroll
    for (int i = 0; i < 4; ++i) {
      const int m = m0 + wm * 128 + mi * 16 + (lane >> 4) * 4 + i;
#pragma unroll
      for (int ni = 0; ni < 4; ++ni) {
        const int n = n0 + wn * 64 + ni * 16 + (lane & 15);
        const float v = acc[mi][ni][i];
        if constexpr (FINAL) {
          atomicAdd(Cf + (size_t)m * N + n, v);
        } else {
          Cb[(size_t)m * N + n] = (bf16)v;
        }
      }
    }
  }
}

// ---------------------------------------------------------------------------
// QK RMSNorm + RoPE; one wave per (s, head). reads fused qkv proj (S x 6144).
// ---------------------------------------------------------------------------
__global__ void qkrope_kernel(const bf16* __restrict__ qkv,
                              const float* __restrict__ qw, const float* __restrict__ kw,
                              const float* __restrict__ cs, const float* __restrict__ sn,
                              bf16* __restrict__ qr, bf16* __restrict__ kr)
{
  const int w = blockIdx.x * 4 + (threadIdx.x >> 6);
  const int lane = threadIdx.x & 63;
  const int s = w / (NQH + NKVH);
  const int hh = w % (NQH + NKVH);
  const bf16* src; bf16* dst; const float* nw;
  if (hh < NQH) {
    src = qkv + (size_t)s * NTOT + hh * DH;
    dst = qr + ((size_t)hh * SEQ + s) * DH;
    nw = qw;
  } else {
    const int h2 = hh - NQH;
    src = qkv + (size_t)s * NTOT + 4096 + h2 * DH;
    dst = kr + ((size_t)h2 * SEQ + s) * DH;
    nw = kw;
  }
  const float x0 = (float)src[lane], x1 = (float)src[lane + 64];
  float ss = x0 * x0 + x1 * x1;
#pragma unroll
  for (int m = 1; m < 64; m <<= 1) ss += __shfl_xor(ss, m);
  const float rn = rsqrtf(ss * (1.f / DH) + 1e-5f);
  const float n0 = x0 * rn * nw[lane], n1 = x1 * rn * nw[lane + 64];
  const float c0 = cs[s * DH + lane],      s0 = sn[s * DH + lane];
  const float c1 = cs[s * DH + lane + 64], s1 = sn[s * DH + lane + 64];
  dst[lane]      = (bf16)(n0 * c0 - n1 * s0);
  dst[lane + 64] = (bf16)(n1 * c1 + n0 * s1);
}

// ---------------------------------------------------------------------------
// V transpose: fused qkv (S, 6144; v at col 5120+h*128) -> (NKV, D, S)
// ---------------------------------------------------------------------------
__global__ void vtrans_kernel(const bf16* __restrict__ qkv, bf16* __restrict__ vt)
{
  __shared__ bf16 tbuf[64][33];
  const int s0 = blockIdx.x * 64;
  const int d0 = blockIdx.y * 32;
  const int h  = blockIdx.z;
  const int tid = threadIdx.x;
  {
    const int col = tid & 31, r0 = tid >> 5;
    for (int r = r0; r < 64; r += 8)
      tbuf[r][col] = qkv[(size_t)(s0 + r) * NTOT + 5120 + h * DH + d0 + col];
  }
  __syncthreads();
  {
    const int sc = tid & 63, dr0 = tid >> 6;
    for (int d = dr0; d < 32; d += 4)
      vt[((size_t)h * DH + d0 + d) * SEQ + s0 + sc] = tbuf[sc][d];
  }
}

// ---------------------------------------------------------------------------
// Flash attention, causal + softcap, GQA (unchanged from round 3).
// ---------------------------------------------------------------------------
__global__ __launch_bounds__(256, 2)
void attn_kernel(const bf16* __restrict__ Q, const bf16* __restrict__ Kr,
                 const bf16* __restrict__ Vt, bf16* __restrict__ Oa)
{
  __shared__ bf16 Ks[2][64 * 128];  // [kv][d], 16-slot swizzle
  __shared__ bf16 Vs[2][128 * 64];  // [d][kv], 8-slot swizzle
  __shared__ bf16 Ps[4][32 * 64];   // per-wave P, 8-slot swizzle

  const int tid = threadIdx.x, lane = tid & 63, wave = tid >> 6;

  const int lin  = blockIdx.x + 16 * blockIdx.y;
  const int slot = lin >> 8, idx = lin & 255;
  const int bx   = slot ? (15 - (idx & 15)) : (idx & 15);
  const int head = (slot << 4) | (idx >> 4);
  const int kvh  = head >> 2;
  const int q0   = bx * 128;
  const int wq0  = q0 + wave * 32;

  const bf16* Qh = Q  + (size_t)head * SEQ * DH;
  const bf16* Kh = Kr + (size_t)kvh * SEQ * DH;
  const bf16* Vh = Vt + (size_t)kvh * DH * SEQ;

  bf16x8 qf[2][4];
#pragma unroll
  for (int mt = 0; mt < 2; ++mt)
#pragma unroll
    for (int kc = 0; kc < 4; ++kc) {
      const int r = wq0 + mt * 16 + (lane & 15);
      qf[mt][kc] = *(const bf16x8*)(Qh + (size_t)r * DH + kc * 32 + (lane >> 4) * 8);
    }

  float lsum[2][4] = {};
  f32x4 o_acc[2][8] = {};

  const int ntiles = q0 / 64 + 2;

  auto stage = [&](int t, int b) {
    const int kv0 = t * 64;
    bf16* Kd = &Ks[b][0];
    bf16* Vd = &Vs[b][0];
#pragma unroll
    for (int i2 = 0; i2 < 4; ++i2) {
      const int c = wave * 4 + i2;
      {
        const int row = c * 4 + (lane >> 4);
        const int col8 = (lane & 15) ^ (row & 15);
        gl2lds16(Kh + (size_t)(kv0 + row) * DH + col8 * 8, Kd + c * 512);
      }
      {
        const int row = c * 8 + (lane >> 3);
        const int col8 = (lane & 7) ^ (row & 7);
        gl2lds16(Vh + (size_t)row * SEQ + kv0 + col8 * 8, Vd + c * 512);
      }
    }
  };

  stage(0, 0);
  __syncthreads();

  const float ZS = RSCALE / SOFTCAP;
  const float A1 = RSCALE * L2E;
  const float B3 = -(ZS * ZS) * (1.f / 3.f);
  const float B5 = (2.f / 15.f) * (ZS * ZS) * (ZS * ZS);
  const float C  = SOFTCAP * L2E;

  for (int t = 0; t < ntiles; ++t) {
    const int cur = t & 1;
    if (t + 1 < ntiles) stage(t + 1, cur ^ 1);
    const int kv0 = t * 64;
    const bf16* Kb = &Ks[cur][0];
    const bf16* Vb = &Vs[cur][0];

    if (kv0 <= wq0 + 31) {
      f32x4 sc[2][4] = {};
      __builtin_amdgcn_s_setprio(1);
#pragma unroll
      for (int ks = 0; ks < 4; ++ks) {
        bf16x8 kf[4];
#pragma unroll
        for (int nt = 0; nt < 4; ++nt) {
          const int row = nt * 16 + (lane & 15);
          const int sl = (ks * 4 + (lane >> 4)) ^ (row & 15);
          kf[nt] = *(const bf16x8*)(Kb + row * 128 + sl * 8);
        }
#pragma unroll
        for (int mt = 0; mt < 2; ++mt)
#pragma unroll
          for (int nt = 0; nt < 4; ++nt)
            sc[mt][nt] = __builtin_amdgcn_mfma_f32_16x16x32_bf16(qf[mt][ks], kf[nt], sc[mt][nt], 0, 0, 0);
      }
      __builtin_amdgcn_s_setprio(0);

      if (kv0 + 63 <= wq0) {
#pragma unroll
        for (int mt = 0; mt < 2; ++mt)
#pragma unroll
          for (int i = 0; i < 4; ++i)
#pragma unroll
            for (int nt = 0; nt < 4; ++nt) {
              const float s = sc[mt][nt][i];
              const float w = s * s;
              const float poly = fmaf(fmaf(B5, w, B3), w, 1.f);
              const float p = __builtin_amdgcn_exp2f(fmaf(s * poly, A1, -C));
              sc[mt][nt][i] = p;
              lsum[mt][i] += p;
            }
      } else {
#pragma unroll
        for (int mt = 0; mt < 2; ++mt)
#pragma unroll
          for (int i = 0; i < 4; ++i) {
            const int qrow = wq0 + mt * 16 + (lane >> 4) * 4 + i;
#pragma unroll
            for (int nt = 0; nt < 4; ++nt) {
              const int col = kv0 + nt * 16 + (lane & 15);
              const float s = sc[mt][nt][i];
              const float w = s * s;
              const float poly = fmaf(fmaf(B5, w, B3), w, 1.f);
              float p = __builtin_amdgcn_exp2f(fmaf(s * poly, A1, -C));
              if (col > qrow) p = 0.f;
              sc[mt][nt][i] = p;
              lsum[mt][i] += p;
            }
          }
      }

#pragma unroll
      for (int mt = 0; mt < 2; ++mt)
#pragma unroll
        for (int nt = 0; nt < 4; ++nt)
#pragma unroll
          for (int i = 0; i < 4; ++i) {
            const int r = mt * 16 + (lane >> 4) * 4 + i;
            const int colb = nt * 16 + (lane & 15);
            const int sl = (colb >> 3) ^ (r & 7);
            Ps[wave][r * 64 + sl * 8 + (colb & 7)] = (bf16)sc[mt][nt][i];
          }
      asm volatile("s_waitcnt lgkmcnt(0)" ::: "memory");
      __builtin_amdgcn_sched_barrier(0);

      __builtin_amdgcn_s_setprio(1);
#pragma unroll
      for (int ks2 = 0; ks2 < 2; ++ks2) {
        bf16x8 pf[2];
#pragma unroll
        for (int mt = 0; mt < 2; ++mt) {
          const int r = mt * 16 + (lane & 15);
          const int sl = (ks2 * 4 + (lane >> 4)) ^ (r & 7);
          pf[mt] = *(const bf16x8*)(&Ps[wave][r * 64 + sl * 8]);
        }
#pragma unroll
        for (int nt = 0; nt < 8; ++nt) {
          const int row = nt * 16 + (lane & 15);
          const int sl = (ks2 * 4 + (lane >> 4)) ^ (row & 7);
          const bf16x8 vf = *(const bf16x8*)(Vb + row * 64 + sl * 8);
          o_acc[0][nt] = __builtin_amdgcn_mfma_f32_16x16x32_bf16(pf[0], vf, o_acc[0][nt], 0, 0, 0);
          o_acc[1][nt] = __builtin_amdgcn_mfma_f32_16x16x32_bf16(pf[1], vf, o_acc[1][nt], 0, 0, 0);
        }
      }
      __builtin_amdgcn_s_setprio(0);
    }
    __syncthreads();
  }

#pragma unroll
  for (int mt = 0; mt < 2; ++mt)
#pragma unroll
    for (int i = 0; i < 4; ++i) {
      float l = lsum[mt][i];
#pragma unroll
      for (int m = 1; m < 16; m <<= 1) l += __shfl_xor(l, m);
      const int qrow = wq0 + mt * 16 + (lane >> 4) * 4 + i;
      const float inv_l = 1.f / l;
#pragma unroll
      for (int nt = 0; nt < 8; ++nt) {
        const int d = nt * 16 + (lane & 15);
        Oa[(size_t)qrow * HID + head * DH + d] = (bf16)(o_acc[mt][nt][i] * inv_l);
      }
    }
}

// ---------------------------------------------------------------------------
// host launcher
// ---------------------------------------------------------------------------
extern "C" void kernel_launch(void* const* d_in, const int* in_sizes, int n_in,
                              void* d_out, int out_size, void* d_ws, size_t ws_size,
                              hipStream_t stream)
{
  const float* hidden = (const float*)d_in[0];
  // d_in[1] = attention_mask (pure causal -1e9; implemented analytically)
  const float* cosb   = (const float*)d_in[2];
  const float* sinb   = (const float*)d_in[3];
  const float* prew   = (const float*)d_in[4];
  const float* wq     = (const float*)d_in[5];
  const float* wk     = (const float*)d_in[6];
  const float* wv     = (const float*)d_in[7];
  const float* wo     = (const float*)d_in[8];
  const float* qnw    = (const float*)d_in[9];
  const float* knw    = (const float*)d_in[10];
  float* outp = (float*)d_out;
  char* ws = (char*)d_ws;

  // workspace layout:
  bf16* wqkv = (bf16*)(ws + 0);          // 50.3 MB : [wq;wk;wv] bf16 (6144x4096); later wo bf16 (33.5 MB)
  bf16* hb   = (bf16*)(ws + 50331648);   // 16.8 MB : normed h; later q-rope (NQ,S,D)
  bf16* qkvp = (bf16*)(ws + 67108864);   // 25.2 MB : fused qkv proj (S x 6144); later attn out
  bf16* kr   = (bf16*)(ws + 92274688);   //  4.2 MB : k-rope (NKV,S,D)
  bf16* vt   = (bf16*)(ws + 96468992);   //  4.2 MB : v transposed (NKV,D,S)
  bf16* wob  = wqkv;                     // wo bf16 reuses wqkv region after QKV GEMM

  cvt_kernel<<<2048, 256, 0, stream>>>(wq, wqkv, 4096 * HID / 4);
  cvt_kernel<<<1024, 256, 0, stream>>>(wk, wqkv + (size_t)4096 * HID, 1024 * HID / 4);
  cvt_kernel<<<1024, 256, 0, stream>>>(wv, wqkv + (size_t)5120 * HID, 1024 * HID / 4);
  rmsnorm_kernel<<<SEQ, 256, 0, stream>>>(hidden, prew, hb, outp);   // also pre-fills d_out with residual

  gemmring<false><<<dim3(NTOT / 256, SEQ / 256, 1), 512, 163840, stream>>>(
      hb, wqkv, qkvp, nullptr, SEQ, NTOT, HID, HID);

  cvt_kernel<<<2048, 256, 0, stream>>>(wo, wob, HID * HID / 4);   // after QKV GEMM

  qkrope_kernel<<<SEQ * (NQH + NKVH) / 4, 256, 0, stream>>>(qkvp, qnw, knw, cosb, sinb, hb, kr);
  vtrans_kernel<<<dim3(32, 4, 8), 256, 0, stream>>>(qkvp, vt);

  attn_kernel<<<dim3(16, 32), 256, 0, stream>>>(hb, kr, vt, qkvp);

  // O-proj: split-K=2 (grid 16x8x2 = 256 blocks = 1/CU), fp32 atomic
  // accumulation into residual-pre-filled d_out.
  gemmring<true><<<dim3(HID / 256, SEQ / 256, 2), 512, 163840, stream>>>(
      qkvp, wob, nullptr, outp, SEQ, HID, HID, HID / 2);
}

// Round 7
// 391.570 us; speedup vs baseline: 1.0195x; 1.0195x over previous
//
#include <hip/hip_runtime.h>
#include <cstdint>

typedef __bf16 bf16;
typedef __bf16 bf16x8 __attribute__((ext_vector_type(8)));
typedef __bf16 bf16x4 __attribute__((ext_vector_type(4)));
typedef float  f32x4  __attribute__((ext_vector_type(4)));

#define SEQ  2048
#define HID  4096
#define DH   128
#define NQH  32
#define NKVH 8
#define NTOT 6144            /* 4096 q + 1024 k + 1024 v */
#define RSCALE 0.08838834764831845f   /* 1/sqrt(128) */
#define SOFTCAP 30.0f
#define L2E 1.4426950408889634f

// async global->LDS, 16B per lane; LDS dest = wave-uniform base + lane*16
__device__ __forceinline__ void gl2lds16(const void* g, void* l) {
  __builtin_amdgcn_global_load_lds(
      (const __attribute__((address_space(1))) unsigned int*)g,
      (__attribute__((address_space(3))) unsigned int*)l, 16, 0, 0);
}

// ---------------------------------------------------------------------------
// fp32 -> bf16 conversion (vectorized)
// ---------------------------------------------------------------------------
__global__ void cvt_kernel(const float* __restrict__ in, bf16* __restrict__ out, int n4) {
  const int stride = gridDim.x * blockDim.x;
  for (int i = blockIdx.x * blockDim.x + threadIdx.x; i < n4; i += stride) {
    const float4 v = ((const float4*)in)[i];
    bf16x4 o = { (bf16)v.x, (bf16)v.y, (bf16)v.z, (bf16)v.w };
    *(bf16x4*)(out + (size_t)i * 4) = o;
  }
}

// ---------------------------------------------------------------------------
// pre-attention RMSNorm: (S,H) fp32 -> bf16; also copies residual into d_out
// (O-proj later accumulates via fp32 atomicAdd on top of it).
// ---------------------------------------------------------------------------
__global__ void rmsnorm_kernel(const float* __restrict__ x, const float* __restrict__ w,
                               bf16* __restrict__ out, float* __restrict__ res_out) {
  const int s = blockIdx.x;
  const float* xr = x + (size_t)s * HID;
  float4 v[4];
  float ss = 0.f;
#pragma unroll
  for (int j = 0; j < 4; ++j) {
    v[j] = ((const float4*)xr)[threadIdx.x + j * 256];
    ss += v[j].x * v[j].x + v[j].y * v[j].y + v[j].z * v[j].z + v[j].w * v[j].w;
  }
#pragma unroll
  for (int m = 1; m < 64; m <<= 1) ss += __shfl_xor(ss, m);
  __shared__ float red[4];
  if ((threadIdx.x & 63) == 0) red[threadIdx.x >> 6] = ss;
  __syncthreads();
  const float rn = rsqrtf((red[0] + red[1] + red[2] + red[3]) * (1.f / HID) + 1e-5f);
  bf16* orow = out + (size_t)s * HID;
  float4* rrow = (float4*)(res_out + (size_t)s * HID);
#pragma unroll
  for (int j = 0; j < 4; ++j) {
    const int idx = (threadIdx.x + j * 256) * 4;
    const float4 wv = ((const float4*)w)[threadIdx.x + j * 256];
    bf16x4 o = { (bf16)(v[j].x * rn * wv.x), (bf16)(v[j].y * rn * wv.y),
                 (bf16)(v[j].z * rn * wv.z), (bf16)(v[j].w * rn * wv.w) };
    *(bf16x4*)(orow + idx) = o;
    rrow[threadIdx.x + j * 256] = v[j];   // residual copy
  }
}

// ---------------------------------------------------------------------------
// m201-faithful 8-phase 256x256 GEMM  C[M,N] = A[M,K] * B[N,K]^T
// 512 threads = 8 waves (2m x 4n), wave tile 128x64, BK=64.
// LDS 128KB = 2 K-tile slots x (A 32KB + B 32KB); rows of 64 bf16 (128B),
// slot-of-8 XOR swizzle (^= row&7) via pre-swizzled global source (R5 layout,
// measured 0 bank conflicts).
// Per K-tile k (slot k&1), 4 phases q0..q3:
//   q0: 8 B-frag ds_reads (held in regs across phases) + 4 A-frag reads,
//       stage A0-half of k+1
//   q1: 4 A-frag reads, stage A1-half of k+1
//   q2: 4 A-frag reads, stage B0-half of k+2
//   q3: 4 A-frag reads, stage B1-half of k+2
//   each phase: barrier; lgkmcnt(0); sched_barrier; setprio(1); 16 MFMA;
//               setprio(0); [q3: vmcnt(4)]; barrier
// Race-freedom: B-halves of a slot are last read at that K-tile's q0 (frags
// held in regs), so re-staging them at q2/q3 is after the q0-end barrier;
// A-halves are last read at q3, re-staged at the NEXT K-tile's q0/q1.
// vmcnt(4) at q3 retires everything through A1(k+1) (so K-tile k+1 is fully
// resident for its q0) while leaving B0/B1(k+2)'s 4 loads in flight - the
// VMEM queue never drains in steady state (T4).
// FINAL: fp32 atomicAdd into Cf (split-K partials; Cf pre-filled w/ residual).
// ---------------------------------------------------------------------------
template<bool FINAL>
__global__ __launch_bounds__(512, 2)
void gemm8p(const bf16* __restrict__ A, const bf16* __restrict__ B,
            bf16* __restrict__ Cb, float* __restrict__ Cf,
            int M, int N, int Ktot, int Klen)
{
  extern __shared__ char smem[];   // 2 x 65536
  const int tid  = threadIdx.x;
  const int lane = tid & 63;
  const int wave = tid >> 6;
  const int wm = wave >> 2, wn = wave & 3;

  // XCD-aware bijective swizzle within a z-slice (nwg % 8 == 0)
  const int gx = gridDim.x;
  const int nwg = gx * gridDim.y;
  int lin = blockIdx.x + gx * blockIdx.y;
  lin = (lin & 7) * (nwg >> 3) + (lin >> 3);
  const int m0 = (lin / gx) * 256;
  const int n0 = (lin % gx) * 256;
  const int k0 = blockIdx.z * Klen;

  // stage one 16KB half: h = {0:A rows 0-127, 1:A rows 128-255,
  //                           2:B rows 0-127, 3:B rows 128-255} at K=kt.
  // 2 gl2lds per thread (16 chunks of 1KB, chunk = wave*2+l).
  auto stageH = [&](int kt, int slot, int h) {
    const bf16* src = (h & 2) ? (B + (size_t)n0 * Ktot) : (A + (size_t)m0 * Ktot);
    char* base = smem + slot * 65536 + (h & 2) * 16384 + (h & 1) * 16384;
    const int r0 = (h & 1) * 128;
#pragma unroll
    for (int l = 0; l < 2; ++l) {
      const int c = wave * 2 + l;
      const int row = r0 + c * 8 + (lane >> 3);
      const int col8 = (lane & 7) ^ (row & 7);
      gl2lds16(src + (size_t)row * Ktot + kt + col8 * 8,
               base + (size_t)c * 1024);
    }
  };

  f32x4 acc[8][4] = {};
  const int nk = Klen / 64;
  const int rl = lane & 15, hi = lane >> 4;

  // prologue: K-tiles 0,1 fully staged, one-time full drain
#pragma unroll
  for (int h = 0; h < 4; ++h) stageH(k0, 0, h);
#pragma unroll
  for (int h = 0; h < 4; ++h) stageH(k0 + 64, 1, h);
  asm volatile("s_waitcnt vmcnt(0)" ::: "memory");
  asm volatile("s_barrier" ::: "memory");

  for (int k = 0; k < nk; ++k) {
    const int slot = k & 1;
    const bf16* Aa = (const bf16*)(smem + slot * 65536);
    const bf16* Ba = (const bf16*)(smem + slot * 65536 + 32768);
    const int kt = k0 + k * 64;
    bf16x8 bfr[4][2];   // B fragments, live across all 4 phases

#pragma unroll
    for (int q = 0; q < 4; ++q) {
      // ---- phase loads (ds_read) ----
      bf16x8 afr[2][2];
#pragma unroll
      for (int mi = 0; mi < 2; ++mi)
#pragma unroll
        for (int ks = 0; ks < 2; ++ks) {
          const int row = wm * 128 + q * 32 + mi * 16 + rl;
          const int slt = (ks * 4 + hi) ^ (row & 7);
          afr[mi][ks] = *(const bf16x8*)(Aa + row * 64 + slt * 8);
        }
      if (q == 0) {
#pragma unroll
        for (int ni = 0; ni < 4; ++ni)
#pragma unroll
          for (int ks = 0; ks < 2; ++ks) {
            const int row = wn * 64 + ni * 16 + rl;
            const int slt = (ks * 4 + hi) ^ (row & 7);
            bfr[ni][ks] = *(const bf16x8*)(Ba + row * 64 + slt * 8);
          }
      }
      // ---- phase staging (1 half-tile = 2 gl2lds) ----
      if (q == 0 && k + 1 < nk) stageH(kt + 64,  (k + 1) & 1, 0);
      if (q == 1 && k + 1 < nk) stageH(kt + 64,  (k + 1) & 1, 1);
      if (q == 2 && k + 2 < nk) stageH(kt + 128, slot, 2);
      if (q == 3 && k + 2 < nk) stageH(kt + 128, slot, 3);

      // ---- compute ----
      asm volatile("s_barrier" ::: "memory");
      asm volatile("s_waitcnt lgkmcnt(0)" ::: "memory");
      __builtin_amdgcn_sched_barrier(0);
      __builtin_amdgcn_s_setprio(1);
#pragma unroll
      for (int ks = 0; ks < 2; ++ks)
#pragma unroll
        for (int mi = 0; mi < 2; ++mi)
#pragma unroll
          for (int ni = 0; ni < 4; ++ni)
            acc[q * 2 + mi][ni] = __builtin_amdgcn_mfma_f32_16x16x32_bf16(
                afr[mi][ks], bfr[ni][ks], acc[q * 2 + mi][ni], 0, 0, 0);
      __builtin_amdgcn_s_setprio(0);

      if (q == 3) {   // once per K-tile: publish K-tile k+1 (counted, no drain)
        if (k + 2 < nk)      { asm volatile("s_waitcnt vmcnt(4)" ::: "memory"); }
        else if (k + 1 < nk) { asm volatile("s_waitcnt vmcnt(0)" ::: "memory"); }
      }
      asm volatile("s_barrier" ::: "memory");
    }
  }

  // epilogue
#pragma unroll
  for (int mi = 0; mi < 8; ++mi) {
#pragma unroll
    for (int i = 0; i < 4; ++i) {
      const int m = m0 + wm * 128 + mi * 16 + (lane >> 4) * 4 + i;
#pragma unroll
      for (int ni = 0; ni < 4; ++ni) {
        const int n = n0 + wn * 64 + ni * 16 + (lane & 15);
        const float v = acc[mi][ni][i];
        if constexpr (FINAL) {
          atomicAdd(Cf + (size_t)m * N + n, v);
        } else {
          Cb[(size_t)m * N + n] = (bf16)v;
        }
      }
    }
  }
}

// ---------------------------------------------------------------------------
// QK RMSNorm + RoPE; one wave per (s, head). reads fused qkv proj (S x 6144).
// ---------------------------------------------------------------------------
__global__ void qkrope_kernel(const bf16* __restrict__ qkv,
                              const float* __restrict__ qw, const float* __restrict__ kw,
                              const float* __restrict__ cs, const float* __restrict__ sn,
                              bf16* __restrict__ qr, bf16* __restrict__ kr)
{
  const int w = blockIdx.x * 4 + (threadIdx.x >> 6);
  const int lane = threadIdx.x & 63;
  const int s = w / (NQH + NKVH);
  const int hh = w % (NQH + NKVH);
  const bf16* src; bf16* dst; const float* nw;
  if (hh < NQH) {
    src = qkv + (size_t)s * NTOT + hh * DH;
    dst = qr + ((size_t)hh * SEQ + s) * DH;
    nw = qw;
  } else {
    const int h2 = hh - NQH;
    src = qkv + (size_t)s * NTOT + 4096 + h2 * DH;
    dst = kr + ((size_t)h2 * SEQ + s) * DH;
    nw = kw;
  }
  const float x0 = (float)src[lane], x1 = (float)src[lane + 64];
  float ss = x0 * x0 + x1 * x1;
#pragma unroll
  for (int m = 1; m < 64; m <<= 1) ss += __shfl_xor(ss, m);
  const float rn = rsqrtf(ss * (1.f / DH) + 1e-5f);
  const float n0 = x0 * rn * nw[lane], n1 = x1 * rn * nw[lane + 64];
  const float c0 = cs[s * DH + lane],      s0 = sn[s * DH + lane];
  const float c1 = cs[s * DH + lane + 64], s1 = sn[s * DH + lane + 64];
  dst[lane]      = (bf16)(n0 * c0 - n1 * s0);
  dst[lane + 64] = (bf16)(n1 * c1 + n0 * s1);
}

// ---------------------------------------------------------------------------
// V transpose: fused qkv (S, 6144; v at col 5120+h*128) -> (NKV, D, S)
// ---------------------------------------------------------------------------
__global__ void vtrans_kernel(const bf16* __restrict__ qkv, bf16* __restrict__ vt)
{
  __shared__ bf16 tbuf[64][33];
  const int s0 = blockIdx.x * 64;
  const int d0 = blockIdx.y * 32;
  const int h  = blockIdx.z;
  const int tid = threadIdx.x;
  {
    const int col = tid & 31, r0 = tid >> 5;
    for (int r = r0; r < 64; r += 8)
      tbuf[r][col] = qkv[(size_t)(s0 + r) * NTOT + 5120 + h * DH + d0 + col];
  }
  __syncthreads();
  {
    const int sc = tid & 63, dr0 = tid >> 6;
    for (int d = dr0; d < 32; d += 4)
      vt[((size_t)h * DH + d0 + d) * SEQ + s0 + sc] = tbuf[sc][d];
  }
}

// ---------------------------------------------------------------------------
// Flash attention, causal + softcap, GQA (unchanged from round 3).
// ---------------------------------------------------------------------------
__global__ __launch_bounds__(256, 2)
void attn_kernel(const bf16* __restrict__ Q, const bf16* __restrict__ Kr,
                 const bf16* __restrict__ Vt, bf16* __restrict__ Oa)
{
  __shared__ bf16 Ks[2][64 * 128];  // [kv][d], 16-slot swizzle
  __shared__ bf16 Vs[2][128 * 64];  // [d][kv], 8-slot swizzle
  __shared__ bf16 Ps[4][32 * 64];   // per-wave P, 8-slot swizzle

  const int tid = threadIdx.x, lane = tid & 63, wave = tid >> 6;

  const int lin  = blockIdx.x + 16 * blockIdx.y;
  const int slot = lin >> 8, idx = lin & 255;
  const int bx   = slot ? (15 - (idx & 15)) : (idx & 15);
  const int head = (slot << 4) | (idx >> 4);
  const int kvh  = head >> 2;
  const int q0   = bx * 128;
  const int wq0  = q0 + wave * 32;

  const bf16* Qh = Q  + (size_t)head * SEQ * DH;
  const bf16* Kh = Kr + (size_t)kvh * SEQ * DH;
  const bf16* Vh = Vt + (size_t)kvh * DH * SEQ;

  bf16x8 qf[2][4];
#pragma unroll
  for (int mt = 0; mt < 2; ++mt)
#pragma unroll
    for (int kc = 0; kc < 4; ++kc) {
      const int r = wq0 + mt * 16 + (lane & 15);
      qf[mt][kc] = *(const bf16x8*)(Qh + (size_t)r * DH + kc * 32 + (lane >> 4) * 8);
    }

  float lsum[2][4] = {};
  f32x4 o_acc[2][8] = {};

  const int ntiles = q0 / 64 + 2;

  auto stage = [&](int t, int b) {
    const int kv0 = t * 64;
    bf16* Kd = &Ks[b][0];
    bf16* Vd = &Vs[b][0];
#pragma unroll
    for (int i2 = 0; i2 < 4; ++i2) {
      const int c = wave * 4 + i2;
      {
        const int row = c * 4 + (lane >> 4);
        const int col8 = (lane & 15) ^ (row & 15);
        gl2lds16(Kh + (size_t)(kv0 + row) * DH + col8 * 8, Kd + c * 512);
      }
      {
        const int row = c * 8 + (lane >> 3);
        const int col8 = (lane & 7) ^ (row & 7);
        gl2lds16(Vh + (size_t)row * SEQ + kv0 + col8 * 8, Vd + c * 512);
      }
    }
  };

  stage(0, 0);
  __syncthreads();

  const float ZS = RSCALE / SOFTCAP;
  const float A1 = RSCALE * L2E;
  const float B3 = -(ZS * ZS) * (1.f / 3.f);
  const float B5 = (2.f / 15.f) * (ZS * ZS) * (ZS * ZS);
  const float C  = SOFTCAP * L2E;

  for (int t = 0; t < ntiles; ++t) {
    const int cur = t & 1;
    if (t + 1 < ntiles) stage(t + 1, cur ^ 1);
    const int kv0 = t * 64;
    const bf16* Kb = &Ks[cur][0];
    const bf16* Vb = &Vs[cur][0];

    if (kv0 <= wq0 + 31) {
      f32x4 sc[2][4] = {};
      __builtin_amdgcn_s_setprio(1);
#pragma unroll
      for (int ks = 0; ks < 4; ++ks) {
        bf16x8 kf[4];
#pragma unroll
        for (int nt = 0; nt < 4; ++nt) {
          const int row = nt * 16 + (lane & 15);
          const int sl = (ks * 4 + (lane >> 4)) ^ (row & 15);
          kf[nt] = *(const bf16x8*)(Kb + row * 128 + sl * 8);
        }
#pragma unroll
        for (int mt = 0; mt < 2; ++mt)
#pragma unroll
          for (int nt = 0; nt < 4; ++nt)
            sc[mt][nt] = __builtin_amdgcn_mfma_f32_16x16x32_bf16(qf[mt][ks], kf[nt], sc[mt][nt], 0, 0, 0);
      }
      __builtin_amdgcn_s_setprio(0);

      if (kv0 + 63 <= wq0) {
#pragma unroll
        for (int mt = 0; mt < 2; ++mt)
#pragma unroll
          for (int i = 0; i < 4; ++i)
#pragma unroll
            for (int nt = 0; nt < 4; ++nt) {
              const float s = sc[mt][nt][i];
              const float w = s * s;
              const float poly = fmaf(fmaf(B5, w, B3), w, 1.f);
              const float p = __builtin_amdgcn_exp2f(fmaf(s * poly, A1, -C));
              sc[mt][nt][i] = p;
              lsum[mt][i] += p;
            }
      } else {
#pragma unroll
        for (int mt = 0; mt < 2; ++mt)
#pragma unroll
          for (int i = 0; i < 4; ++i) {
            const int qrow = wq0 + mt * 16 + (lane >> 4) * 4 + i;
#pragma unroll
            for (int nt = 0; nt < 4; ++nt) {
              const int col = kv0 + nt * 16 + (lane & 15);
              const float s = sc[mt][nt][i];
              const float w = s * s;
              const float poly = fmaf(fmaf(B5, w, B3), w, 1.f);
              float p = __builtin_amdgcn_exp2f(fmaf(s * poly, A1, -C));
              if (col > qrow) p = 0.f;
              sc[mt][nt][i] = p;
              lsum[mt][i] += p;
            }
          }
      }

#pragma unroll
      for (int mt = 0; mt < 2; ++mt)
#pragma unroll
        for (int nt = 0; nt < 4; ++nt)
#pragma unroll
          for (int i = 0; i < 4; ++i) {
            const int r = mt * 16 + (lane >> 4) * 4 + i;
            const int colb = nt * 16 + (lane & 15);
            const int sl = (colb >> 3) ^ (r & 7);
            Ps[wave][r * 64 + sl * 8 + (colb & 7)] = (bf16)sc[mt][nt][i];
          }
      asm volatile("s_waitcnt lgkmcnt(0)" ::: "memory");
      __builtin_amdgcn_sched_barrier(0);

      __builtin_amdgcn_s_setprio(1);
#pragma unroll
      for (int ks2 = 0; ks2 < 2; ++ks2) {
        bf16x8 pf[2];
#pragma unroll
        for (int mt = 0; mt < 2; ++mt) {
          const int r = mt * 16 + (lane & 15);
          const int sl = (ks2 * 4 + (lane >> 4)) ^ (r & 7);
          pf[mt] = *(const bf16x8*)(&Ps[wave][r * 64 + sl * 8]);
        }
#pragma unroll
        for (int nt = 0; nt < 8; ++nt) {
          const int row = nt * 16 + (lane & 15);
          const int sl = (ks2 * 4 + (lane >> 4)) ^ (row & 7);
          const bf16x8 vf = *(const bf16x8*)(Vb + row * 64 + sl * 8);
          o_acc[0][nt] = __builtin_amdgcn_mfma_f32_16x16x32_bf16(pf[0], vf, o_acc[0][nt], 0, 0, 0);
          o_acc[1][nt] = __builtin_amdgcn_mfma_f32_16x16x32_bf16(pf[1], vf, o_acc[1][nt], 0, 0, 0);
        }
      }
      __builtin_amdgcn_s_setprio(0);
    }
    __syncthreads();
  }

#pragma unroll
  for (int mt = 0; mt < 2; ++mt)
#pragma unroll
    for (int i = 0; i < 4; ++i) {
      float l = lsum[mt][i];
#pragma unroll
      for (int m = 1; m < 16; m <<= 1) l += __shfl_xor(l, m);
      const int qrow = wq0 + mt * 16 + (lane >> 4) * 4 + i;
      const float inv_l = 1.f / l;
#pragma unroll
      for (int nt = 0; nt < 8; ++nt) {
        const int d = nt * 16 + (lane & 15);
        Oa[(size_t)qrow * HID + head * DH + d] = (bf16)(o_acc[mt][nt][i] * inv_l);
      }
    }
}

// ---------------------------------------------------------------------------
// host launcher
// ---------------------------------------------------------------------------
extern "C" void kernel_launch(void* const* d_in, const int* in_sizes, int n_in,
                              void* d_out, int out_size, void* d_ws, size_t ws_size,
                              hipStream_t stream)
{
  const float* hidden = (const float*)d_in[0];
  // d_in[1] = attention_mask (pure causal -1e9; implemented analytically)
  const float* cosb   = (const float*)d_in[2];
  const float* sinb   = (const float*)d_in[3];
  const float* prew   = (const float*)d_in[4];
  const float* wq     = (const float*)d_in[5];
  const float* wk     = (const float*)d_in[6];
  const float* wv     = (const float*)d_in[7];
  const float* wo     = (const float*)d_in[8];
  const float* qnw    = (const float*)d_in[9];
  const float* knw    = (const float*)d_in[10];
  float* outp = (float*)d_out;
  char* ws = (char*)d_ws;

  // workspace layout:
  bf16* wqkv = (bf16*)(ws + 0);          // 50.3 MB : [wq;wk;wv] bf16 (6144x4096); later wo bf16 (33.5 MB)
  bf16* hb   = (bf16*)(ws + 50331648);   // 16.8 MB : normed h; later q-rope (NQ,S,D)
  bf16* qkvp = (bf16*)(ws + 67108864);   // 25.2 MB : fused qkv proj (S x 6144); later attn out
  bf16* kr   = (bf16*)(ws + 92274688);   //  4.2 MB : k-rope (NKV,S,D)
  bf16* vt   = (bf16*)(ws + 96468992);   //  4.2 MB : v transposed (NKV,D,S)
  bf16* wob  = wqkv;                     // wo bf16 reuses wqkv region after QKV GEMM

  cvt_kernel<<<2048, 256, 0, stream>>>(wq, wqkv, 4096 * HID / 4);
  cvt_kernel<<<1024, 256, 0, stream>>>(wk, wqkv + (size_t)4096 * HID, 1024 * HID / 4);
  cvt_kernel<<<1024, 256, 0, stream>>>(wv, wqkv + (size_t)5120 * HID, 1024 * HID / 4);
  rmsnorm_kernel<<<SEQ, 256, 0, stream>>>(hidden, prew, hb, outp);   // also pre-fills d_out with residual

  gemm8p<false><<<dim3(NTOT / 256, SEQ / 256, 1), 512, 131072, stream>>>(
      hb, wqkv, qkvp, nullptr, SEQ, NTOT, HID, HID);

  cvt_kernel<<<2048, 256, 0, stream>>>(wo, wob, HID * HID / 4);   // after QKV GEMM

  qkrope_kernel<<<SEQ * (NQH + NKVH) / 4, 256, 0, stream>>>(qkvp, qnw, knw, cosb, sinb, hb, kr);
  vtrans_kernel<<<dim3(32, 4, 8), 256, 0, stream>>>(qkvp, vt);

  attn_kernel<<<dim3(16, 32), 256, 0, stream>>>(hb, kr, vt, qkvp);

  // O-proj: split-K=2 (grid 16x8x2 = 256 blocks = 1/CU), fp32 atomic
  // accumulation into residual-pre-filled d_out.
  gemm8p<true><<<dim3(HID / 256, SEQ / 256, 2), 512, 131072, stream>>>(
      qkvp, wob, nullptr, outp, SEQ, HID, HID, HID / 2);
}